// Round 11
// baseline (3388.504 us; speedup 1.0000x reference)
//
#include <hip/hip_runtime.h>
#include <hip/hip_bf16.h>

typedef _Float16 fp16_t;
typedef _Float16 v8h __attribute__((ext_vector_type(8)));
typedef float    v4f __attribute__((ext_vector_type(4)));

#define RELAX_LR 0.3f

// async global->LDS, 16B per lane. LDS dest = wave-uniform base + lane*16.
__device__ __forceinline__ void async_cp16(const void* g, void* l) {
    __builtin_amdgcn_global_load_lds(
        (const __attribute__((address_space(1))) void*)g,
        (__attribute__((address_space(3))) void*)l, 16, 0, 0);
}

// ---------------------------------------------------------------------------
// Split-K GEMM into fp16 partials (fp32 MFMA accumulate, one rounding at
// store). Fwd section: z<nz1 -> A1*B1t^T chunk z*CK1; bwd: A2*B2t^T chunk
// (z-nz1)*CK2. Tile BM=128 x BN=128 x BK=64, **128 thr = 2 waves, each wave
// 64x128** (4x8 of 16x16x32 f16 MFMA): A fragments read once, only B
// duplicated -> LDS issue 48 KB/block-iter (1156 cyc/CU at 85 B/cyc) < MFMA
// 1240 cyc -> MFMA-bound (the 4-wave layout was LDS-issue-bound at 64 KB).
// Double-buffered LDS 64 KB -> 2 blocks/CU. 1-D grid of 512, XCD-swizzled
// decode (blk%8 = XCD; z pinned per XCD so B-tiles+A-chunk are L2-resident).
// ---------------------------------------------------------------------------
__global__ __launch_bounds__(128, 1) void gemm_splitk_kernel(
    const fp16_t* __restrict__ A1, const fp16_t* __restrict__ B1t, int K1, int CK1, int nz1,
    const fp16_t* __restrict__ A2, const fp16_t* __restrict__ B2t, int K2s, int CK2,
    fp16_t* __restrict__ part, int Ntot)
{
    __shared__ __align__(16) fp16_t As[2][2][128][32];  // [stage][khalf][row][col]
    __shared__ __align__(16) fp16_t Bs[2][2][128][32];

    const int tid  = threadIdx.x;
    const int lane = tid & 63;
    const int w    = tid >> 6;         // wave 0..1: m-half (64 rows), full n=128
    const int quad = lane >> 4;
    const int lrow = lane & 15;

    // swizzled decode: blk%8 = XCD; c = (bn,z) combo pinned to one XCD.
    const int blk  = blockIdx.x;
    const int low3 = blk & 7;
    const int g    = blk >> 3;
    const int bm   = g & 7;
    const int c    = (g >> 3) * 8 + low3;   // 0..63
    int bn, z;
    if (Ntot == 2048) { bn = c >> 2; z = c & 3; }   // 16 bn x 4 z
    else              { bn = c >> 3; z = c & 7; }   // 8 bn x 8 z

    const fp16_t *A, *Bt; int stride, koff, CK;
    if (z < nz1) { A = A1; Bt = B1t; stride = K1;  CK = CK1; koff = z * CK1; }
    else         { A = A2; Bt = B2t; stride = K2s; CK = CK2; koff = (z - nz1) * CK2; }

    // staging: each cp16 = 16 rows x 32 fp16 (1 KB/wave), lane -> (row=lane/4,
    // col=(lane&3)*8) matches LDS base + lane*16. Wave w stages khalf w of
    // both A and B: 16 cp16/wave per stage (32 KB/block-stage).
    const int sr = lane >> 2;
    const int sc = (lane & 3) * 8;
    const fp16_t* ag = A  + (size_t)(bm * 128 + sr) * stride + koff + sc + w * 32;
    const fp16_t* bg = Bt + (size_t)(bn * 128 + sr) * stride + koff + sc + w * 32;
    const size_t st16 = (size_t)16 * stride;

    v4f acc[4][8] = {};
    const int iters = CK >> 6;         // BK = 64

    auto stage = [&](int buf, int kb) {
        const fp16_t* a0 = ag + kb;
        const fp16_t* b0 = bg + kb;
        #pragma unroll
        for (int gi = 0; gi < 8; ++gi) {
            async_cp16(a0 + gi * st16, &As[buf][w][16 * gi][0]);
            async_cp16(b0 + gi * st16, &Bs[buf][w][16 * gi][0]);
        }
    };

    stage(0, 0);                       // prologue: tile 0 -> buffer 0

    for (int it = 0; it < iters; ++it) {
        __syncthreads();   // drains vmcnt -> buf (it&1) ready; prior ds_reads done
        if (it + 1 < iters) stage((it + 1) & 1, (it + 1) * 64);
        const int cur = it & 1;
        #pragma unroll
        for (int h = 0; h < 2; ++h) {
            v8h af[4], bv[8];
            #pragma unroll
            for (int fm = 0; fm < 4; ++fm)
                af[fm] = *(const v8h*)&As[cur][h][w * 64 + fm * 16 + lrow][quad * 8];
            #pragma unroll
            for (int fn = 0; fn < 8; ++fn)
                bv[fn] = *(const v8h*)&Bs[cur][h][fn * 16 + lrow][quad * 8];
            #pragma unroll
            for (int fm = 0; fm < 4; ++fm)
                #pragma unroll
                for (int fn = 0; fn < 8; ++fn)
                    acc[fm][fn] = __builtin_amdgcn_mfma_f32_16x16x32_f16(
                        af[fm], bv[fn], acc[fm][fn], 0, 0, 0);
        }
    }

    // write fp16 partials. C/D layout: col = lane&15, row = quad*4 + reg.
    fp16_t* po = part + (size_t)z * 1024 * Ntot;
    const int rowbase = bm * 128 + w * 64 + quad * 4;
    const int colbase = bn * 128;
    #pragma unroll
    for (int fn = 0; fn < 8; ++fn) {
        const int col = colbase + fn * 16 + lrow;
        #pragma unroll
        for (int fm = 0; fm < 4; ++fm) {
            const int row = rowbase + fm * 16;
            #pragma unroll
            for (int r = 0; r < 4; ++r)
                po[(size_t)(row + r) * Ntot + col] = (fp16_t)acc[fm][fn][r];
        }
    }
}

// ---------------------------------------------------------------------------
// Sum nz fp16 partial slices (fp32 accumulate) + bias, init/update + clip,
// fp16 state write. 8 elements/thread, 16B loads. s_old may alias outb
// (same-thread RMW). If finout != nullptr, also writes the fp32 output
// stripped to [1024,1000] (the 1000-col boundary is 8-aligned; this fuses
// the old out_copy kernel into the final layer-4 reduce).
// ---------------------------------------------------------------------------
__global__ __launch_bounds__(256) void reduce_update_kernel(
    const fp16_t* __restrict__ part, int nz,
    const float* __restrict__ bias, const fp16_t* s_old,
    fp16_t* outb, int Ntot, int do_update, int total8,
    float* __restrict__ finout)
{
    const int i = blockIdx.x * 256 + threadIdx.x;
    if (i >= total8) return;
    const size_t e = (size_t)i * 8;

    float v[8];
    {
        const v8h p0 = *(const v8h*)(part + e);
        #pragma unroll
        for (int j = 0; j < 8; ++j) v[j] = (float)p0[j];
    }
    for (int z = 1; z < nz; ++z) {
        const v8h p = *(const v8h*)(part + (size_t)z * 1024 * Ntot + e);
        #pragma unroll
        for (int j = 0; j < 8; ++j) v[j] += (float)p[j];
    }
    const int col = (int)e & (Ntot - 1);
    const float4 b0 = *(const float4*)(bias + col);
    const float4 b1 = *(const float4*)(bias + col + 4);
    v[0] += b0.x; v[1] += b0.y; v[2] += b0.z; v[3] += b0.w;
    v[4] += b1.x; v[5] += b1.y; v[6] += b1.z; v[7] += b1.w;
    if (do_update) {
        const v8h so = *(const v8h*)(s_old + e);
        #pragma unroll
        for (int j = 0; j < 8; ++j) {
            const float s = (float)so[j];
            v[j] = s + RELAX_LR * (v[j] - s);
        }
    }
    #pragma unroll
    for (int j = 0; j < 8; ++j) v[j] = fminf(fmaxf(v[j], 0.f), 1.f);
    v8h h;
    #pragma unroll
    for (int j = 0; j < 8; ++j) h[j] = (fp16_t)v[j];
    *(v8h*)(outb + e) = h;

    if (finout && col < 1000) {
        const int row = (int)(e >> 10);          // Ntot == 1024 on this path
        float* o = finout + (size_t)row * 1000 + col;
        float4 o0 = {v[0], v[1], v[2], v[3]};
        float4 o1 = {v[4], v[5], v[6], v[7]};
        *(float4*)o       = o0;
        *(float4*)(o + 4) = o1;
    }
}

// fp32 W [R,C] -> fp16 Wb [Rp,Cp] (optional) + fp16 WbT [Cp,Rp], zero-padded.
__global__ void conv_w_kernel(const float* __restrict__ W, int R, int C,
                              fp16_t* Wb, fp16_t* __restrict__ WbT,
                              int Rp, int Cp)
{
    __shared__ float t[32][33];
    const int tx = threadIdx.x & 31;
    const int ty = threadIdx.x >> 5;   // 0..7
    const int r0 = blockIdx.y * 32;
    const int c0 = blockIdx.x * 32;
    #pragma unroll
    for (int i = 0; i < 4; ++i) {
        const int r = r0 + ty + i * 8;
        const int c = c0 + tx;
        float v = 0.f;
        if (r < R && c < C) v = W[(size_t)r * C + c];
        t[ty + i * 8][tx] = v;
    }
    __syncthreads();
    if (Wb) {
        #pragma unroll
        for (int i = 0; i < 4; ++i) {
            const int r = r0 + ty + i * 8;
            const int c = c0 + tx;
            if (r < Rp && c < Cp) Wb[(size_t)r * Cp + c] = (fp16_t)t[ty + i * 8][tx];
        }
    }
    #pragma unroll
    for (int i = 0; i < 4; ++i) {
        const int cc = c0 + ty + i * 8;
        const int rr = r0 + tx;
        if (cc < Cp && rr < Rp) WbT[(size_t)cc * Rp + rr] = (fp16_t)t[tx][ty + i * 8];
    }
}

__global__ void conv_x_kernel(const float* __restrict__ x,
                              fp16_t* __restrict__ xb, fp16_t* __restrict__ rxb, int n)
{
    const int i = blockIdx.x * blockDim.x + threadIdx.x;
    if (i < n) {
        const float v = x[i];
        xb[i]  = (fp16_t)v;
        rxb[i] = (fp16_t)fminf(fmaxf(v, 0.f), 1.f);
    }
}

__global__ void pad_b4_kernel(const float* __restrict__ b4, float* __restrict__ b4p)
{
    const int i = blockIdx.x * blockDim.x + threadIdx.x;
    if (i < 1024) b4p[i] = (i < 1000) ? b4[i] : 0.f;
}

extern "C" void kernel_launch(void* const* d_in, const int* in_sizes, int n_in,
                              void* d_out, int out_size, void* d_ws, size_t ws_size,
                              hipStream_t stream)
{
    const float* x  = (const float*)d_in[0];
    const float* W0 = (const float*)d_in[1];
    const float* W1 = (const float*)d_in[2];
    const float* W2 = (const float*)d_in[3];
    const float* W3 = (const float*)d_in[4];
    const float* b1 = (const float*)d_in[5];
    const float* b2 = (const float*)d_in[6];
    const float* b3 = (const float*)d_in[7];
    const float* b4 = (const float*)d_in[8];
    float* out = (float*)d_out;

    char* p = (char*)d_ws;
    auto alloc = [&](size_t bytes) {
        char* q = p;
        p += (bytes + 255) & ~(size_t)255;
        return q;
    };

    fp16_t* xb   = (fp16_t*)alloc((size_t)1024 * 2048 * 2);
    fp16_t* rxb  = (fp16_t*)alloc((size_t)1024 * 2048 * 2);
    fp16_t* Wb1  = (fp16_t*)alloc((size_t)2048 * 2048 * 2);
    fp16_t* Wb2  = (fp16_t*)alloc((size_t)2048 * 2048 * 2);
    fp16_t* Wb3  = (fp16_t*)alloc((size_t)2048 * 1024 * 2);   // padded cols
    fp16_t* WbT0 = (fp16_t*)alloc((size_t)2048 * 2048 * 2);
    fp16_t* WbT1 = (fp16_t*)alloc((size_t)2048 * 2048 * 2);
    fp16_t* WbT2 = (fp16_t*)alloc((size_t)2048 * 2048 * 2);
    fp16_t* WbT3 = (fp16_t*)alloc((size_t)1024 * 2048 * 2);   // padded rows
    fp16_t* s1b  = (fp16_t*)alloc((size_t)1024 * 2048 * 2);
    fp16_t* s2b  = (fp16_t*)alloc((size_t)1024 * 2048 * 2);
    fp16_t* s3b  = (fp16_t*)alloc((size_t)1024 * 2048 * 2);
    fp16_t* s4b  = (fp16_t*)alloc((size_t)1024 * 1024 * 2);
    float*  b4p  = (float*)alloc(1024 * 4);
    fp16_t* part = (fp16_t*)alloc((size_t)4 * 1024 * 2048 * 2); // 16 MB, reused
    (void)ws_size; (void)in_sizes; (void)n_in; (void)out_size;

    // --- setup conversions ---
    conv_x_kernel<<<(1024 * 2048 + 255) / 256, 256, 0, stream>>>(x, xb, rxb, 1024 * 2048);
    pad_b4_kernel<<<4, 256, 0, stream>>>(b4, b4p);
    conv_w_kernel<<<dim3(64, 64), 256, 0, stream>>>(W0, 2048, 2048, nullptr, WbT0, 2048, 2048);
    conv_w_kernel<<<dim3(64, 64), 256, 0, stream>>>(W1, 2048, 2048, Wb1, WbT1, 2048, 2048);
    conv_w_kernel<<<dim3(64, 64), 256, 0, stream>>>(W2, 2048, 2048, Wb2, WbT2, 2048, 2048);
    conv_w_kernel<<<dim3(32, 64), 256, 0, stream>>>(W3, 2048, 1000, Wb3, WbT3, 2048, 1024);

    const dim3 gblk(128);               // GEMM: 2 waves/block
    const dim3 g512(512);               // all GEMMs: 512 blocks, swizzled decode
    const dim3 rblk(256);
    const int t8_2048 = 1024 * 2048 / 8;
    const int t8_1024 = 1024 * 1024 / 8;
    const int rg2048 = t8_2048 / 256;   // 1024 blocks
    const int rg1024 = t8_1024 / 256;   // 512 blocks

    // --- feedforward init: s_l = clip(s_{l-1} @ W_{l-1} + b_l) ---
    gemm_splitk_kernel<<<g512, gblk, 0, stream>>>(xb,  WbT0, 2048, 512, 4, nullptr, nullptr, 0, 0, part, 2048);
    reduce_update_kernel<<<rg2048, rblk, 0, stream>>>(part, 4, b1, nullptr, s1b, 2048, 0, t8_2048, nullptr);
    gemm_splitk_kernel<<<g512, gblk, 0, stream>>>(s1b, WbT1, 2048, 512, 4, nullptr, nullptr, 0, 0, part, 2048);
    reduce_update_kernel<<<rg2048, rblk, 0, stream>>>(part, 4, b2, nullptr, s2b, 2048, 0, t8_2048, nullptr);
    gemm_splitk_kernel<<<g512, gblk, 0, stream>>>(s2b, WbT2, 2048, 512, 4, nullptr, nullptr, 0, 0, part, 2048);
    reduce_update_kernel<<<rg2048, rblk, 0, stream>>>(part, 4, b3, nullptr, s3b, 2048, 0, t8_2048, nullptr);
    gemm_splitk_kernel<<<g512, gblk, 0, stream>>>(s3b, WbT3, 2048, 256, 8, nullptr, nullptr, 0, 0, part, 1024);
    reduce_update_kernel<<<rg1024, rblk, 0, stream>>>(part, 8, b4p, nullptr, s4b, 1024, 0, t8_1024, nullptr);

    // --- 25 Gauss-Seidel sweeps (states post-rho => rho identity on them) ---
    for (int it = 0; it < 25; ++it) {
        // layer 1: rho(x)@W0 (K=2048, 2x1024) + s2@W1^T (K=2048, 2x1024)
        gemm_splitk_kernel<<<g512, gblk, 0, stream>>>(rxb, WbT0, 2048, 1024, 2, s2b, Wb1, 2048, 1024, part, 2048);
        reduce_update_kernel<<<rg2048, rblk, 0, stream>>>(part, 4, b1, s1b, s1b, 2048, 1, t8_2048, nullptr);
        // layer 2: s1@W1 + s3@W2^T
        gemm_splitk_kernel<<<g512, gblk, 0, stream>>>(s1b, WbT1, 2048, 1024, 2, s3b, Wb2, 2048, 1024, part, 2048);
        reduce_update_kernel<<<rg2048, rblk, 0, stream>>>(part, 4, b2, s2b, s2b, 2048, 1, t8_2048, nullptr);
        // layer 3: s2@W2 (2x1024) + s4@W3^T (K=1024, 2x512) — balanced z=4
        gemm_splitk_kernel<<<g512, gblk, 0, stream>>>(s2b, WbT2, 2048, 1024, 2, s4b, Wb3, 1024, 512, part, 2048);
        reduce_update_kernel<<<rg2048, rblk, 0, stream>>>(part, 4, b3, s3b, s3b, 2048, 1, t8_2048, nullptr);
        // layer 4: s3@W3 (K=2048, 8x256); final sweep also writes d_out
        gemm_splitk_kernel<<<g512, gblk, 0, stream>>>(s3b, WbT3, 2048, 256, 8, nullptr, nullptr, 0, 0, part, 1024);
        reduce_update_kernel<<<rg1024, rblk, 0, stream>>>(part, 8, b4p, s4b, s4b, 1024, 1, t8_1024,
                                                          (it == 24) ? out : nullptr);
    }
}

// Round 12
// 2756.875 us; speedup vs baseline: 1.2291x; 1.2291x over previous
//
#include <hip/hip_runtime.h>
#include <hip/hip_bf16.h>

typedef _Float16 fp16_t;
typedef _Float16 v8h __attribute__((ext_vector_type(8)));
typedef float    v4f __attribute__((ext_vector_type(4)));

#define RELAX_LR 0.3f

// async global->LDS, 16B per lane. LDS dest = wave-uniform base + lane*16.
__device__ __forceinline__ void async_cp16(const void* g, void* l) {
    __builtin_amdgcn_global_load_lds(
        (const __attribute__((address_space(1))) void*)g,
        (__attribute__((address_space(3))) void*)l, 16, 0, 0);
}

// ---------------------------------------------------------------------------
// Split-K GEMM into fp16 partials (fp32 MFMA accumulate, one rounding at
// store). Fwd section: z<nz1 -> A1*B1t^T chunk z*CK1; bwd: A2*B2t^T chunk
// (z-nz1)*CK2. Tile BM=128 x BN=128 x BK=64, 256 thr = 4 waves, each wave
// 64x64 (4x4 16x16x32 f16 MFMA). Double-buffered LDS 64 KB -> 2 blocks/CU
// (= 8 waves/CU; r11's 2-wave variant at 4 waves/CU regressed 19% — wave
// count for latency hiding beats LDS-byte accounting). 1-D grid of 512,
// XCD-swizzled decode (blk%8 = XCD; z pinned per XCD -> ~4MB L2 working set).
// ---------------------------------------------------------------------------
__global__ __launch_bounds__(256, 2) void gemm_splitk_kernel(
    const fp16_t* __restrict__ A1, const fp16_t* __restrict__ B1t, int K1, int CK1, int nz1,
    const fp16_t* __restrict__ A2, const fp16_t* __restrict__ B2t, int K2s, int CK2,
    fp16_t* __restrict__ part, int Ntot)
{
    __shared__ __align__(16) fp16_t As[2][2][128][32];  // [stage][khalf][row][col]
    __shared__ __align__(16) fp16_t Bs[2][2][128][32];

    const int tid  = threadIdx.x;
    const int lane = tid & 63;
    const int w    = tid >> 6;         // wave 0..3
    const int wm   = w >> 1;           // m-half (64 rows)
    const int wn   = w & 1;            // n-half (64 cols)
    const int quad = lane >> 4;
    const int lrow = lane & 15;

    // swizzled decode: blk%8 = XCD; c = (bn,z) combo pinned to one XCD.
    const int blk  = blockIdx.x;
    const int low3 = blk & 7;
    const int g    = blk >> 3;
    const int bm   = g & 7;
    const int c    = (g >> 3) * 8 + low3;   // 0..63
    int bn, z;
    if (Ntot == 2048) { bn = c >> 2; z = c & 3; }   // 16 bn x 4 z
    else              { bn = c >> 3; z = c & 7; }   // 8 bn x 8 z

    const fp16_t *A, *Bt; int stride, koff, CK;
    if (z < nz1) { A = A1; Bt = B1t; stride = K1;  CK = CK1; koff = z * CK1; }
    else         { A = A2; Bt = B2t; stride = K2s; CK = CK2; koff = (z - nz1) * CK2; }

    // staging: each cp16 = 16 rows x 32 fp16 (1 KB/wave), lane -> (row=lane/4,
    // col=(lane&3)*8) matches LDS base + lane*16. Wave w owns rows
    // [32w,32w+32) of A and B for both khalves: 8 cp16/wave per stage.
    const int sr = lane >> 2;
    const int sc = (lane & 3) * 8;
    const fp16_t* ag = A  + (size_t)(bm * 128 + 32 * w + sr) * stride + koff + sc;
    const fp16_t* bg = Bt + (size_t)(bn * 128 + 32 * w + sr) * stride + koff + sc;
    const size_t st16 = (size_t)16 * stride;

    v4f acc[4][4] = {};
    const int iters = CK >> 6;         // BK = 64

    auto stage = [&](int buf, int kb) {
        const fp16_t* a0 = ag + kb;
        const fp16_t* b0 = bg + kb;
        async_cp16(a0,             &As[buf][0][32 * w     ][0]);
        async_cp16(a0 + st16,      &As[buf][0][32 * w + 16][0]);
        async_cp16(a0 + 32,        &As[buf][1][32 * w     ][0]);
        async_cp16(a0 + 32 + st16, &As[buf][1][32 * w + 16][0]);
        async_cp16(b0,             &Bs[buf][0][32 * w     ][0]);
        async_cp16(b0 + st16,      &Bs[buf][0][32 * w + 16][0]);
        async_cp16(b0 + 32,        &Bs[buf][1][32 * w     ][0]);
        async_cp16(b0 + 32 + st16, &Bs[buf][1][32 * w + 16][0]);
    };

    stage(0, 0);                       // prologue: tile 0 -> buffer 0

    for (int it = 0; it < iters; ++it) {
        __syncthreads();   // drains vmcnt -> buf (it&1) ready; prior ds_reads done
        if (it + 1 < iters) stage((it + 1) & 1, (it + 1) * 64);
        const int cur = it & 1;
        #pragma unroll
        for (int h = 0; h < 2; ++h) {
            v8h af[4], bv[4];
            #pragma unroll
            for (int fm = 0; fm < 4; ++fm)
                af[fm] = *(const v8h*)&As[cur][h][wm * 64 + fm * 16 + lrow][quad * 8];
            #pragma unroll
            for (int fn = 0; fn < 4; ++fn)
                bv[fn] = *(const v8h*)&Bs[cur][h][wn * 64 + fn * 16 + lrow][quad * 8];
            #pragma unroll
            for (int fm = 0; fm < 4; ++fm)
                #pragma unroll
                for (int fn = 0; fn < 4; ++fn)
                    acc[fm][fn] = __builtin_amdgcn_mfma_f32_16x16x32_f16(
                        af[fm], bv[fn], acc[fm][fn], 0, 0, 0);
        }
    }

    // write fp16 partials. C/D layout: col = lane&15, row = quad*4 + reg.
    fp16_t* po = part + (size_t)z * 1024 * Ntot;
    const int rowbase = bm * 128 + wm * 64 + quad * 4;
    const int colbase = bn * 128 + wn * 64;
    #pragma unroll
    for (int fn = 0; fn < 4; ++fn) {
        const int col = colbase + fn * 16 + lrow;
        #pragma unroll
        for (int fm = 0; fm < 4; ++fm) {
            const int row = rowbase + fm * 16;
            #pragma unroll
            for (int r = 0; r < 4; ++r)
                po[(size_t)(row + r) * Ntot + col] = (fp16_t)acc[fm][fn][r];
        }
    }
}

// ---------------------------------------------------------------------------
// Sum nz fp16 partial slices (fp32 accumulate) + (bias[col] OR per-element
// fp32 extra, e.g. the hoisted c1 = b1 + rho(x)@W0), init/update + clip,
// fp16 state write. 8 elements/thread, 16B loads. s_old may alias outb.
// If finout != nullptr also writes fp32 output stripped to [1024,1000].
// ---------------------------------------------------------------------------
__global__ __launch_bounds__(256) void reduce_update_kernel(
    const fp16_t* __restrict__ part, int nz,
    const float* __restrict__ bias, const float* __restrict__ extra,
    const fp16_t* s_old, fp16_t* outb,
    int Ntot, int do_update, int total8, float* __restrict__ finout)
{
    const int i = blockIdx.x * 256 + threadIdx.x;
    if (i >= total8) return;
    const size_t e = (size_t)i * 8;

    float v[8];
    {
        const v8h p0 = *(const v8h*)(part + e);
        #pragma unroll
        for (int j = 0; j < 8; ++j) v[j] = (float)p0[j];
    }
    for (int z = 1; z < nz; ++z) {
        const v8h p = *(const v8h*)(part + (size_t)z * 1024 * Ntot + e);
        #pragma unroll
        for (int j = 0; j < 8; ++j) v[j] += (float)p[j];
    }
    const int col = (int)e & (Ntot - 1);
    if (extra) {
        const float4 e0 = *(const float4*)(extra + e);
        const float4 e1 = *(const float4*)(extra + e + 4);
        v[0] += e0.x; v[1] += e0.y; v[2] += e0.z; v[3] += e0.w;
        v[4] += e1.x; v[5] += e1.y; v[6] += e1.z; v[7] += e1.w;
    } else {
        const float4 b0 = *(const float4*)(bias + col);
        const float4 b1 = *(const float4*)(bias + col + 4);
        v[0] += b0.x; v[1] += b0.y; v[2] += b0.z; v[3] += b0.w;
        v[4] += b1.x; v[5] += b1.y; v[6] += b1.z; v[7] += b1.w;
    }
    if (do_update) {
        const v8h so = *(const v8h*)(s_old + e);
        #pragma unroll
        for (int j = 0; j < 8; ++j) {
            const float s = (float)so[j];
            v[j] = s + RELAX_LR * (v[j] - s);
        }
    }
    #pragma unroll
    for (int j = 0; j < 8; ++j) v[j] = fminf(fmaxf(v[j], 0.f), 1.f);
    v8h h;
    #pragma unroll
    for (int j = 0; j < 8; ++j) h[j] = (fp16_t)v[j];
    *(v8h*)(outb + e) = h;

    if (finout && col < 1000) {
        const int row = (int)(e >> 10);          // Ntot == 1024 on this path
        float* o = finout + (size_t)row * 1000 + col;
        float4 o0 = {v[0], v[1], v[2], v[3]};
        float4 o1 = {v[4], v[5], v[6], v[7]};
        *(float4*)o       = o0;
        *(float4*)(o + 4) = o1;
    }
}

// c1f = sum of 4 fp16 partial slices + bias (fp32, no clip): the
// loop-invariant layer-1 constant b1 + rho(x)@W0, computed once.
__global__ __launch_bounds__(256) void makec1_kernel(
    const fp16_t* __restrict__ part, const float* __restrict__ bias,
    float* __restrict__ c1f, int total8)
{
    const int i = blockIdx.x * 256 + threadIdx.x;
    if (i >= total8) return;
    const size_t e = (size_t)i * 8;
    float v[8];
    {
        const v8h p0 = *(const v8h*)(part + e);
        #pragma unroll
        for (int j = 0; j < 8; ++j) v[j] = (float)p0[j];
    }
    #pragma unroll
    for (int z = 1; z < 4; ++z) {
        const v8h p = *(const v8h*)(part + (size_t)z * 1024 * 2048 + e);
        #pragma unroll
        for (int j = 0; j < 8; ++j) v[j] += (float)p[j];
    }
    const int col = (int)e & 2047;
    const float4 b0 = *(const float4*)(bias + col);
    const float4 b1 = *(const float4*)(bias + col + 4);
    v[0] += b0.x; v[1] += b0.y; v[2] += b0.z; v[3] += b0.w;
    v[4] += b1.x; v[5] += b1.y; v[6] += b1.z; v[7] += b1.w;
    float4 o0 = {v[0], v[1], v[2], v[3]};
    float4 o1 = {v[4], v[5], v[6], v[7]};
    *(float4*)(c1f + e)     = o0;
    *(float4*)(c1f + e + 4) = o1;
}

// fp32 W [R,C] -> fp16 Wb [Rp,Cp] (optional) + fp16 WbT [Cp,Rp], zero-padded.
__global__ void conv_w_kernel(const float* __restrict__ W, int R, int C,
                              fp16_t* Wb, fp16_t* __restrict__ WbT,
                              int Rp, int Cp)
{
    __shared__ float t[32][33];
    const int tx = threadIdx.x & 31;
    const int ty = threadIdx.x >> 5;   // 0..7
    const int r0 = blockIdx.y * 32;
    const int c0 = blockIdx.x * 32;
    #pragma unroll
    for (int i = 0; i < 4; ++i) {
        const int r = r0 + ty + i * 8;
        const int c = c0 + tx;
        float v = 0.f;
        if (r < R && c < C) v = W[(size_t)r * C + c];
        t[ty + i * 8][tx] = v;
    }
    __syncthreads();
    if (Wb) {
        #pragma unroll
        for (int i = 0; i < 4; ++i) {
            const int r = r0 + ty + i * 8;
            const int c = c0 + tx;
            if (r < Rp && c < Cp) Wb[(size_t)r * Cp + c] = (fp16_t)t[ty + i * 8][tx];
        }
    }
    #pragma unroll
    for (int i = 0; i < 4; ++i) {
        const int cc = c0 + ty + i * 8;
        const int rr = r0 + tx;
        if (cc < Cp && rr < Rp) WbT[(size_t)cc * Rp + rr] = (fp16_t)t[tx][ty + i * 8];
    }
}

__global__ void conv_x_kernel(const float* __restrict__ x,
                              fp16_t* __restrict__ xb, fp16_t* __restrict__ rxb, int n)
{
    const int i = blockIdx.x * blockDim.x + threadIdx.x;
    if (i < n) {
        const float v = x[i];
        xb[i]  = (fp16_t)v;
        rxb[i] = (fp16_t)fminf(fmaxf(v, 0.f), 1.f);
    }
}

__global__ void pad_b4_kernel(const float* __restrict__ b4, float* __restrict__ b4p)
{
    const int i = blockIdx.x * blockDim.x + threadIdx.x;
    if (i < 1024) b4p[i] = (i < 1000) ? b4[i] : 0.f;
}

extern "C" void kernel_launch(void* const* d_in, const int* in_sizes, int n_in,
                              void* d_out, int out_size, void* d_ws, size_t ws_size,
                              hipStream_t stream)
{
    const float* x  = (const float*)d_in[0];
    const float* W0 = (const float*)d_in[1];
    const float* W1 = (const float*)d_in[2];
    const float* W2 = (const float*)d_in[3];
    const float* W3 = (const float*)d_in[4];
    const float* b1 = (const float*)d_in[5];
    const float* b2 = (const float*)d_in[6];
    const float* b3 = (const float*)d_in[7];
    const float* b4 = (const float*)d_in[8];
    float* out = (float*)d_out;

    char* p = (char*)d_ws;
    auto alloc = [&](size_t bytes) {
        char* q = p;
        p += (bytes + 255) & ~(size_t)255;
        return q;
    };

    fp16_t* xb   = (fp16_t*)alloc((size_t)1024 * 2048 * 2);
    fp16_t* rxb  = (fp16_t*)alloc((size_t)1024 * 2048 * 2);
    fp16_t* Wb1  = (fp16_t*)alloc((size_t)2048 * 2048 * 2);
    fp16_t* Wb2  = (fp16_t*)alloc((size_t)2048 * 2048 * 2);
    fp16_t* Wb3  = (fp16_t*)alloc((size_t)2048 * 1024 * 2);   // padded cols
    fp16_t* WbT0 = (fp16_t*)alloc((size_t)2048 * 2048 * 2);
    fp16_t* WbT1 = (fp16_t*)alloc((size_t)2048 * 2048 * 2);
    fp16_t* WbT2 = (fp16_t*)alloc((size_t)2048 * 2048 * 2);
    fp16_t* WbT3 = (fp16_t*)alloc((size_t)1024 * 2048 * 2);   // padded rows
    fp16_t* s1b  = (fp16_t*)alloc((size_t)1024 * 2048 * 2);
    fp16_t* s2b  = (fp16_t*)alloc((size_t)1024 * 2048 * 2);
    fp16_t* s3b  = (fp16_t*)alloc((size_t)1024 * 2048 * 2);
    fp16_t* s4b  = (fp16_t*)alloc((size_t)1024 * 1024 * 2);
    float*  b4p  = (float*)alloc(1024 * 4);
    float*  c1f  = (float*)alloc((size_t)1024 * 2048 * 4);    // hoisted b1+rho(x)@W0
    fp16_t* part = (fp16_t*)alloc((size_t)4 * 1024 * 2048 * 2); // 16 MB, reused
    (void)ws_size; (void)in_sizes; (void)n_in; (void)out_size;

    // --- setup conversions ---
    conv_x_kernel<<<(1024 * 2048 + 255) / 256, 256, 0, stream>>>(x, xb, rxb, 1024 * 2048);
    pad_b4_kernel<<<4, 256, 0, stream>>>(b4, b4p);
    conv_w_kernel<<<dim3(64, 64), 256, 0, stream>>>(W0, 2048, 2048, nullptr, WbT0, 2048, 2048);
    conv_w_kernel<<<dim3(64, 64), 256, 0, stream>>>(W1, 2048, 2048, Wb1, WbT1, 2048, 2048);
    conv_w_kernel<<<dim3(64, 64), 256, 0, stream>>>(W2, 2048, 2048, Wb2, WbT2, 2048, 2048);
    conv_w_kernel<<<dim3(32, 64), 256, 0, stream>>>(W3, 2048, 1000, Wb3, WbT3, 2048, 1024);

    const dim3 blk(256);
    const dim3 g512(512);               // all GEMMs: 512 blocks, swizzled decode
    const int t8_2048 = 1024 * 2048 / 8;
    const int t8_1024 = 1024 * 1024 / 8;
    const int rg2048 = t8_2048 / 256;   // 1024 blocks
    const int rg1024 = t8_1024 / 256;   // 512 blocks

    // --- hoisted layer-1 constant: c1f = b1 + rho(x)@W0 (once, reused 25x) ---
    gemm_splitk_kernel<<<g512, blk, 0, stream>>>(rxb, WbT0, 2048, 512, 4, nullptr, nullptr, 0, 0, part, 2048);
    makec1_kernel<<<rg2048, blk, 0, stream>>>(part, b1, c1f, t8_2048);

    // --- feedforward init: s_l = clip(s_{l-1} @ W_{l-1} + b_l) ---
    gemm_splitk_kernel<<<g512, blk, 0, stream>>>(xb,  WbT0, 2048, 512, 4, nullptr, nullptr, 0, 0, part, 2048);
    reduce_update_kernel<<<rg2048, blk, 0, stream>>>(part, 4, b1, nullptr, nullptr, s1b, 2048, 0, t8_2048, nullptr);
    gemm_splitk_kernel<<<g512, blk, 0, stream>>>(s1b, WbT1, 2048, 512, 4, nullptr, nullptr, 0, 0, part, 2048);
    reduce_update_kernel<<<rg2048, blk, 0, stream>>>(part, 4, b2, nullptr, nullptr, s2b, 2048, 0, t8_2048, nullptr);
    gemm_splitk_kernel<<<g512, blk, 0, stream>>>(s2b, WbT2, 2048, 512, 4, nullptr, nullptr, 0, 0, part, 2048);
    reduce_update_kernel<<<rg2048, blk, 0, stream>>>(part, 4, b3, nullptr, nullptr, s3b, 2048, 0, t8_2048, nullptr);
    gemm_splitk_kernel<<<g512, blk, 0, stream>>>(s3b, WbT3, 2048, 256, 8, nullptr, nullptr, 0, 0, part, 1024);
    reduce_update_kernel<<<rg1024, blk, 0, stream>>>(part, 8, b4p, nullptr, nullptr, s4b, 1024, 0, t8_1024, nullptr);

    // --- 25 Gauss-Seidel sweeps (states post-rho => rho identity on them) ---
    for (int it = 0; it < 25; ++it) {
        // layer 1: c1f + s2@W1^T (K=2048, 4x512) — fwd term hoisted
        gemm_splitk_kernel<<<g512, blk, 0, stream>>>(s2b, Wb1, 2048, 512, 4, nullptr, nullptr, 0, 0, part, 2048);
        reduce_update_kernel<<<rg2048, blk, 0, stream>>>(part, 4, nullptr, c1f, s1b, s1b, 2048, 1, t8_2048, nullptr);
        // layer 2: s1@W1 (2x1024) + s3@W2^T (2x1024)
        gemm_splitk_kernel<<<g512, blk, 0, stream>>>(s1b, WbT1, 2048, 1024, 2, s3b, Wb2, 2048, 1024, part, 2048);
        reduce_update_kernel<<<rg2048, blk, 0, stream>>>(part, 4, b2, nullptr, s2b, s2b, 2048, 1, t8_2048, nullptr);
        // layer 3: s2@W2 (2x1024) + s4@W3^T (K=1024, 2x512) — balanced z=4
        gemm_splitk_kernel<<<g512, blk, 0, stream>>>(s2b, WbT2, 2048, 1024, 2, s4b, Wb3, 1024, 512, part, 2048);
        reduce_update_kernel<<<rg2048, blk, 0, stream>>>(part, 4, b3, nullptr, s3b, s3b, 2048, 1, t8_2048, nullptr);
        // layer 4: s3@W3 (K=2048, 8x256); final sweep also writes d_out
        gemm_splitk_kernel<<<g512, blk, 0, stream>>>(s3b, WbT3, 2048, 256, 8, nullptr, nullptr, 0, 0, part, 1024);
        reduce_update_kernel<<<rg1024, blk, 0, stream>>>(part, 8, b4p, nullptr, s4b, s4b, 1024, 1, t8_1024,
                                                         (it == 24) ? out : nullptr);
    }
}

// Round 13
// 2412.298 us; speedup vs baseline: 1.4047x; 1.1428x over previous
//
#include <hip/hip_runtime.h>
#include <hip/hip_bf16.h>

typedef _Float16 fp16_t;
typedef _Float16 v8h __attribute__((ext_vector_type(8)));
typedef float    v4f __attribute__((ext_vector_type(4)));

#define RELAX_LR 0.3f

// async global->LDS, 16B per lane. LDS dest = wave-uniform base + lane*16.
__device__ __forceinline__ void async_cp16(const void* g, void* l) {
    __builtin_amdgcn_global_load_lds(
        (const __attribute__((address_space(1))) void*)g,
        (__attribute__((address_space(3))) void*)l, 16, 0, 0);
}

// GEMM job: C_partial(z) = A1*B1t^T (concat K-space [0,K1)) ++ A2*B2t^T
// ([K1,K1+K2s)). Chunk z covers [z*CK,(z+1)*CK) and MAY cross the section
// boundary (both K1 and chunks are multiples of BK=64, so a BK-tile never
// straddles; pointer select per BK-iter is block-uniform scalar work).
struct GJob {
    const fp16_t *A1, *B1t, *A2, *B2t;
    fp16_t* part;
    int K1, K2s, CK, Ntot;
};

// ---------------------------------------------------------------------------
// Two-job split-K GEMM into fp16 partials (fp32 MFMA accumulate, one rounding
// at store). Blocks [0,nb0) run j0, [nb0,grid) run j1 (pass j0==j1,nb0=grid
// for single-job). Tile BM=128 x BN=128 x BK=64, 256 thr = 4 waves, each wave
// 64x64 (4x4 16x16x32 f16 MFMA). Double-buffered LDS 64 KB -> 2 blocks/CU
// (8 waves/CU; fewer waves regressed 19% in r11). XCD-swizzled decode
// (blk%8 = XCD; z pinned per XCD -> ~4MB L2 working set).
// ---------------------------------------------------------------------------
__global__ __launch_bounds__(256, 2) void gemm_splitk_kernel(GJob j0, GJob j1, int nb0)
{
    __shared__ __align__(16) fp16_t As[2][2][128][32];  // [stage][khalf][row][col]
    __shared__ __align__(16) fp16_t Bs[2][2][128][32];

    const int tid  = threadIdx.x;
    const int lane = tid & 63;
    const int w    = tid >> 6;         // wave 0..3
    const int wm   = w >> 1;           // m-half (64 rows)
    const int wn   = w & 1;            // n-half (64 cols)
    const int quad = lane >> 4;
    const int lrow = lane & 15;

    int bblk = blockIdx.x;
    const GJob j = (bblk < nb0) ? j0 : j1;       // block-uniform
    if (bblk >= nb0) bblk -= nb0;

    // swizzled decode: bblk%8 = XCD; c = (bn,z) combo pinned to one XCD.
    const int low3 = bblk & 7;
    const int g    = bblk >> 3;
    const int bm   = g & 7;
    const int c    = (g >> 3) * 8 + low3;   // 0..63
    int bn, z;
    if (j.Ntot == 2048) { bn = c >> 2; z = c & 3; }   // 16 bn x 4 z
    else                { bn = c >> 3; z = c & 7; }   // 8 bn x 8 z
    const int k0 = z * j.CK;

    // staging: each cp16 = 16 rows x 32 fp16 (1 KB/wave), lane -> (row=lane/4,
    // col=(lane&3)*8) matches LDS base + lane*16. Wave w owns rows
    // [32w,32w+32) of A and B for both khalves: 8 cp16/wave per stage.
    const int sr = lane >> 2;
    const int sc = (lane & 3) * 8;
    const size_t rowA = (size_t)(bm * 128 + 32 * w + sr);
    const size_t rowB = (size_t)(bn * 128 + 32 * w + sr);
    const fp16_t* a1 = j.A1  + rowA * j.K1 + sc;
    const fp16_t* b1 = j.B1t + rowB * j.K1 + sc;
    const fp16_t* a2 = j.A2  ? j.A2  + rowA * j.K2s + sc : nullptr;
    const fp16_t* b2 = j.B2t ? j.B2t + rowB * j.K2s + sc : nullptr;
    const size_t s16a = (size_t)16 * j.K1;
    const size_t s16b = (size_t)16 * j.K2s;

    auto stage = [&](int buf, int kc) {
        const fp16_t *a0, *b0; size_t st;
        if (kc < j.K1) { a0 = a1 + kc;          b0 = b1 + kc;          st = s16a; }
        else           { a0 = a2 + (kc - j.K1); b0 = b2 + (kc - j.K1); st = s16b; }
        async_cp16(a0,           &As[buf][0][32 * w     ][0]);
        async_cp16(a0 + st,      &As[buf][0][32 * w + 16][0]);
        async_cp16(a0 + 32,      &As[buf][1][32 * w     ][0]);
        async_cp16(a0 + 32 + st, &As[buf][1][32 * w + 16][0]);
        async_cp16(b0,           &Bs[buf][0][32 * w     ][0]);
        async_cp16(b0 + st,      &Bs[buf][0][32 * w + 16][0]);
        async_cp16(b0 + 32,      &Bs[buf][1][32 * w     ][0]);
        async_cp16(b0 + 32 + st, &Bs[buf][1][32 * w + 16][0]);
    };

    v4f acc[4][4] = {};
    const int iters = j.CK >> 6;       // BK = 64

    stage(0, k0);                      // prologue: tile 0 -> buffer 0

    for (int it = 0; it < iters; ++it) {
        __syncthreads();   // drains vmcnt -> buf (it&1) ready; prior ds_reads done
        if (it + 1 < iters) stage((it + 1) & 1, k0 + (it + 1) * 64);
        const int cur = it & 1;
        #pragma unroll
        for (int h = 0; h < 2; ++h) {
            v8h af[4], bv[4];
            #pragma unroll
            for (int fm = 0; fm < 4; ++fm)
                af[fm] = *(const v8h*)&As[cur][h][wm * 64 + fm * 16 + lrow][quad * 8];
            #pragma unroll
            for (int fn = 0; fn < 4; ++fn)
                bv[fn] = *(const v8h*)&Bs[cur][h][wn * 64 + fn * 16 + lrow][quad * 8];
            #pragma unroll
            for (int fm = 0; fm < 4; ++fm)
                #pragma unroll
                for (int fn = 0; fn < 4; ++fn)
                    acc[fm][fn] = __builtin_amdgcn_mfma_f32_16x16x32_f16(
                        af[fm], bv[fn], acc[fm][fn], 0, 0, 0);
        }
    }

    // write fp16 partials. C/D layout: col = lane&15, row = quad*4 + reg.
    fp16_t* po = j.part + (size_t)z * 1024 * j.Ntot;
    const int rowbase = bm * 128 + wm * 64 + quad * 4;
    const int colbase = bn * 128 + wn * 64;
    #pragma unroll
    for (int fn = 0; fn < 4; ++fn) {
        const int col = colbase + fn * 16 + lrow;
        #pragma unroll
        for (int fm = 0; fm < 4; ++fm) {
            const int row = rowbase + fm * 16;
            #pragma unroll
            for (int r = 0; r < 4; ++r)
                po[(size_t)(row + r) * j.Ntot + col] = (fp16_t)acc[fm][fn][r];
        }
    }
}

// Reduce job: sum nz fp16 partial slices + (bias[col] OR per-element fp32
// extra), optional relax-update vs s_old, clip, fp16 state write; optional
// fp32 final output stripped to [1024,1000].
struct RJob {
    const fp16_t* part;
    const float* bias;
    const float* extra;
    const fp16_t* s_old;
    fp16_t* outb;
    float* finout;
    int nz, Ntot, do_update;
};

__global__ __launch_bounds__(256) void reduce_update_kernel(RJob j0, RJob j1, int nb0)
{
    int b = blockIdx.x;
    const RJob j = (b < nb0) ? j0 : j1;          // block-uniform
    if (b >= nb0) b -= nb0;
    const size_t e = ((size_t)b * 256 + threadIdx.x) * 8;  // grids sized exactly

    float v[8];
    {
        const v8h p0 = *(const v8h*)(j.part + e);
        #pragma unroll
        for (int k = 0; k < 8; ++k) v[k] = (float)p0[k];
    }
    for (int z = 1; z < j.nz; ++z) {
        const v8h p = *(const v8h*)(j.part + (size_t)z * 1024 * j.Ntot + e);
        #pragma unroll
        for (int k = 0; k < 8; ++k) v[k] += (float)p[k];
    }
    const int col = (int)e & (j.Ntot - 1);
    if (j.extra) {
        const float4 e0 = *(const float4*)(j.extra + e);
        const float4 e1 = *(const float4*)(j.extra + e + 4);
        v[0] += e0.x; v[1] += e0.y; v[2] += e0.z; v[3] += e0.w;
        v[4] += e1.x; v[5] += e1.y; v[6] += e1.z; v[7] += e1.w;
    } else {
        const float4 b0 = *(const float4*)(j.bias + col);
        const float4 b1 = *(const float4*)(j.bias + col + 4);
        v[0] += b0.x; v[1] += b0.y; v[2] += b0.z; v[3] += b0.w;
        v[4] += b1.x; v[5] += b1.y; v[6] += b1.z; v[7] += b1.w;
    }
    if (j.do_update) {
        const v8h so = *(const v8h*)(j.s_old + e);
        #pragma unroll
        for (int k = 0; k < 8; ++k) {
            const float s = (float)so[k];
            v[k] = s + RELAX_LR * (v[k] - s);
        }
    }
    #pragma unroll
    for (int k = 0; k < 8; ++k) v[k] = fminf(fmaxf(v[k], 0.f), 1.f);
    v8h h;
    #pragma unroll
    for (int k = 0; k < 8; ++k) h[k] = (fp16_t)v[k];
    *(v8h*)(j.outb + e) = h;

    if (j.finout && col < 1000) {
        const int row = (int)(e >> 10);          // Ntot == 1024 on this path
        float* o = j.finout + (size_t)row * 1000 + col;
        float4 o0 = {v[0], v[1], v[2], v[3]};
        float4 o1 = {v[4], v[5], v[6], v[7]};
        *(float4*)o       = o0;
        *(float4*)(o + 4) = o1;
    }
}

// c1f = sum of 4 fp16 partial slices + bias (fp32, no clip): the
// loop-invariant layer-1 constant b1 + rho(x)@W0, computed once.
__global__ __launch_bounds__(256) void makec1_kernel(
    const fp16_t* __restrict__ part, const float* __restrict__ bias,
    float* __restrict__ c1f, int total8)
{
    const int i = blockIdx.x * 256 + threadIdx.x;
    if (i >= total8) return;
    const size_t e = (size_t)i * 8;
    float v[8];
    {
        const v8h p0 = *(const v8h*)(part + e);
        #pragma unroll
        for (int k = 0; k < 8; ++k) v[k] = (float)p0[k];
    }
    #pragma unroll
    for (int z = 1; z < 4; ++z) {
        const v8h p = *(const v8h*)(part + (size_t)z * 1024 * 2048 + e);
        #pragma unroll
        for (int k = 0; k < 8; ++k) v[k] += (float)p[k];
    }
    const int col = (int)e & 2047;
    const float4 b0 = *(const float4*)(bias + col);
    const float4 b1 = *(const float4*)(bias + col + 4);
    v[0] += b0.x; v[1] += b0.y; v[2] += b0.z; v[3] += b0.w;
    v[4] += b1.x; v[5] += b1.y; v[6] += b1.z; v[7] += b1.w;
    float4 o0 = {v[0], v[1], v[2], v[3]};
    float4 o1 = {v[4], v[5], v[6], v[7]};
    *(float4*)(c1f + e)     = o0;
    *(float4*)(c1f + e + 4) = o1;
}

// fp32 W [R,C] -> fp16 Wb [Rp,Cp] (optional) + fp16 WbT [Cp,Rp], zero-padded.
__global__ void conv_w_kernel(const float* __restrict__ W, int R, int C,
                              fp16_t* Wb, fp16_t* __restrict__ WbT,
                              int Rp, int Cp)
{
    __shared__ float t[32][33];
    const int tx = threadIdx.x & 31;
    const int ty = threadIdx.x >> 5;   // 0..7
    const int r0 = blockIdx.y * 32;
    const int c0 = blockIdx.x * 32;
    #pragma unroll
    for (int i = 0; i < 4; ++i) {
        const int r = r0 + ty + i * 8;
        const int c = c0 + tx;
        float v = 0.f;
        if (r < R && c < C) v = W[(size_t)r * C + c];
        t[ty + i * 8][tx] = v;
    }
    __syncthreads();
    if (Wb) {
        #pragma unroll
        for (int i = 0; i < 4; ++i) {
            const int r = r0 + ty + i * 8;
            const int c = c0 + tx;
            if (r < Rp && c < Cp) Wb[(size_t)r * Cp + c] = (fp16_t)t[ty + i * 8][tx];
        }
    }
    #pragma unroll
    for (int i = 0; i < 4; ++i) {
        const int cc = c0 + ty + i * 8;
        const int rr = r0 + tx;
        if (cc < Cp && rr < Rp) WbT[(size_t)cc * Rp + rr] = (fp16_t)t[tx][ty + i * 8];
    }
}

__global__ void conv_x_kernel(const float* __restrict__ x,
                              fp16_t* __restrict__ xb, fp16_t* __restrict__ rxb, int n)
{
    const int i = blockIdx.x * blockDim.x + threadIdx.x;
    if (i < n) {
        const float v = x[i];
        xb[i]  = (fp16_t)v;
        rxb[i] = (fp16_t)fminf(fmaxf(v, 0.f), 1.f);
    }
}

__global__ void pad_b4_kernel(const float* __restrict__ b4, float* __restrict__ b4p)
{
    const int i = blockIdx.x * blockDim.x + threadIdx.x;
    if (i < 1024) b4p[i] = (i < 1000) ? b4[i] : 0.f;
}

extern "C" void kernel_launch(void* const* d_in, const int* in_sizes, int n_in,
                              void* d_out, int out_size, void* d_ws, size_t ws_size,
                              hipStream_t stream)
{
    const float* x  = (const float*)d_in[0];
    const float* W0 = (const float*)d_in[1];
    const float* W1 = (const float*)d_in[2];
    const float* W2 = (const float*)d_in[3];
    const float* W3 = (const float*)d_in[4];
    const float* b1 = (const float*)d_in[5];
    const float* b2 = (const float*)d_in[6];
    const float* b3 = (const float*)d_in[7];
    const float* b4 = (const float*)d_in[8];
    float* out = (float*)d_out;

    char* p = (char*)d_ws;
    auto alloc = [&](size_t bytes) {
        char* q = p;
        p += (bytes + 255) & ~(size_t)255;
        return q;
    };

    fp16_t* xb    = (fp16_t*)alloc((size_t)1024 * 2048 * 2);
    fp16_t* rxb   = (fp16_t*)alloc((size_t)1024 * 2048 * 2);
    fp16_t* Wb1   = (fp16_t*)alloc((size_t)2048 * 2048 * 2);
    fp16_t* Wb2   = (fp16_t*)alloc((size_t)2048 * 2048 * 2);
    fp16_t* Wb3   = (fp16_t*)alloc((size_t)2048 * 1024 * 2);   // padded cols
    fp16_t* WbT0  = (fp16_t*)alloc((size_t)2048 * 2048 * 2);
    fp16_t* WbT1  = (fp16_t*)alloc((size_t)2048 * 2048 * 2);
    fp16_t* WbT2  = (fp16_t*)alloc((size_t)2048 * 2048 * 2);
    fp16_t* WbT3  = (fp16_t*)alloc((size_t)1024 * 2048 * 2);   // padded rows
    fp16_t* s1b   = (fp16_t*)alloc((size_t)1024 * 2048 * 2);
    fp16_t* s2b   = (fp16_t*)alloc((size_t)1024 * 2048 * 2);
    fp16_t* s3b   = (fp16_t*)alloc((size_t)1024 * 2048 * 2);
    fp16_t* s4b   = (fp16_t*)alloc((size_t)1024 * 1024 * 2);
    float*  b4p   = (float*)alloc(1024 * 4);
    float*  c1f   = (float*)alloc((size_t)1024 * 2048 * 4);    // hoisted b1+rho(x)@W0
    fp16_t* partA = (fp16_t*)alloc((size_t)8 * 1024 * 1024 * 2); // 16 MB (L4 jobs)
    fp16_t* partB = (fp16_t*)alloc((size_t)4 * 1024 * 2048 * 2); // 16 MB (L1-3 jobs)
    (void)ws_size; (void)in_sizes; (void)n_in; (void)out_size;

    // --- setup conversions ---
    conv_x_kernel<<<(1024 * 2048 + 255) / 256, 256, 0, stream>>>(x, xb, rxb, 1024 * 2048);
    pad_b4_kernel<<<4, 256, 0, stream>>>(b4, b4p);
    conv_w_kernel<<<dim3(64, 64), 256, 0, stream>>>(W0, 2048, 2048, nullptr, WbT0, 2048, 2048);
    conv_w_kernel<<<dim3(64, 64), 256, 0, stream>>>(W1, 2048, 2048, Wb1, WbT1, 2048, 2048);
    conv_w_kernel<<<dim3(64, 64), 256, 0, stream>>>(W2, 2048, 2048, Wb2, WbT2, 2048, 2048);
    conv_w_kernel<<<dim3(32, 64), 256, 0, stream>>>(W3, 2048, 1000, Wb3, WbT3, 2048, 1024);

    const dim3 blk(256);
    const int rg2048 = 1024 * 2048 / 8 / 256;   // 1024 blocks
    const int rg1024 = 1024 * 1024 / 8 / 256;   // 512 blocks

    // --- GEMM jobs (A1,B1t,A2,B2t,part,K1,K2s,CK,Ntot) ---
    const GJob jC1 = { rxb, WbT0, nullptr, nullptr, partA, 2048, 0,    512,  2048 };
    const GJob jI1 = { xb,  WbT0, nullptr, nullptr, partB, 2048, 0,    512,  2048 };
    const GJob jI2 = { s1b, WbT1, nullptr, nullptr, partB, 2048, 0,    512,  2048 };
    const GJob jI3 = { s2b, WbT2, nullptr, nullptr, partB, 2048, 0,    512,  2048 };
    const GJob jI4 = { s3b, WbT3, nullptr, nullptr, partA, 2048, 0,    256,  1024 };
    const GJob jL1 = { s2b, Wb1,  nullptr, nullptr, partB, 2048, 0,    512,  2048 };
    const GJob jL2 = { s1b, WbT1, s3b, Wb2,         partB, 2048, 2048, 1024, 2048 };
    const GJob jL3 = { s2b, WbT2, s4b, Wb3,         partB, 2048, 1024, 768,  2048 }; // balanced 4x768, chunk 2 crosses
    const GJob jL4 = { s3b, WbT3, nullptr, nullptr, partA, 2048, 0,    256,  1024 };

    // --- reduce jobs (part,bias,extra,s_old,outb,finout,nz,Ntot,do_update) ---
    const RJob rI1 = { partB, b1,  nullptr, nullptr, s1b, nullptr, 4, 2048, 0 };
    const RJob rI2 = { partB, b2,  nullptr, nullptr, s2b, nullptr, 4, 2048, 0 };
    const RJob rI3 = { partB, b3,  nullptr, nullptr, s3b, nullptr, 4, 2048, 0 };
    const RJob rI4 = { partA, b4p, nullptr, nullptr, s4b, nullptr, 8, 1024, 0 };
    const RJob rL1 = { partB, nullptr, c1f, s1b, s1b, nullptr, 4, 2048, 1 };
    const RJob rL2 = { partB, b2,  nullptr, s2b, s2b, nullptr, 4, 2048, 1 };
    const RJob rL3 = { partB, b3,  nullptr, s3b, s3b, nullptr, 4, 2048, 1 };
    const RJob rL4 = { partA, b4p, nullptr, s4b, s4b, nullptr, 8, 1024, 1 };
    RJob rL4f = rL4; rL4f.finout = out;

    // --- hoisted layer-1 constant: c1f = b1 + rho(x)@W0 (once, reused 25x) ---
    gemm_splitk_kernel<<<512, blk, 0, stream>>>(jC1, jC1, 512);
    makec1_kernel<<<rg2048, blk, 0, stream>>>(partA, b1, c1f, 1024 * 2048 / 8);

    // --- feedforward init: s_l = clip(s_{l-1} @ W_{l-1} + b_l) ---
    gemm_splitk_kernel<<<512, blk, 0, stream>>>(jI1, jI1, 512);
    reduce_update_kernel<<<rg2048, blk, 0, stream>>>(rI1, rI1, rg2048);
    gemm_splitk_kernel<<<512, blk, 0, stream>>>(jI2, jI2, 512);
    reduce_update_kernel<<<rg2048, blk, 0, stream>>>(rI2, rI2, rg2048);
    gemm_splitk_kernel<<<512, blk, 0, stream>>>(jI3, jI3, 512);
    reduce_update_kernel<<<rg2048, blk, 0, stream>>>(rI3, rI3, rg2048);
    gemm_splitk_kernel<<<512, blk, 0, stream>>>(jI4, jI4, 512);
    reduce_update_kernel<<<rg1024, blk, 0, stream>>>(rI4, rI4, rg1024);

    // --- 25 Gauss-Seidel sweeps. Layer order per sweep is L1,L2,L3,L4, but
    // L4(sweep it) and L1(sweep it+1) are mutually independent (L4 reads s3,
    // L1 reads s2 + c1f) -> merged into one GEMM + one reduce dispatch. ---
    gemm_splitk_kernel<<<512, blk, 0, stream>>>(jL1, jL1, 512);          // L1, sweep 0
    reduce_update_kernel<<<rg2048, blk, 0, stream>>>(rL1, rL1, rg2048);
    for (int it = 0; it < 25; ++it) {
        gemm_splitk_kernel<<<512, blk, 0, stream>>>(jL2, jL2, 512);
        reduce_update_kernel<<<rg2048, blk, 0, stream>>>(rL2, rL2, rg2048);
        gemm_splitk_kernel<<<512, blk, 0, stream>>>(jL3, jL3, 512);
        reduce_update_kernel<<<rg2048, blk, 0, stream>>>(rL3, rL3, rg2048);
        if (it < 24) {
            gemm_splitk_kernel<<<1024, blk, 0, stream>>>(jL4, jL1, 512); // L4 + next L1
            reduce_update_kernel<<<rg1024 + rg2048, blk, 0, stream>>>(rL4, rL1, rg1024);
        } else {
            gemm_splitk_kernel<<<512, blk, 0, stream>>>(jL4, jL4, 512);
            reduce_update_kernel<<<rg1024, blk, 0, stream>>>(rL4f, rL4f, rg1024);
        }
    }
}